// Round 22
// baseline (10276.417 us; speedup 1.0000x reference)
//
#include <hip/hip_runtime.h>
#include <cstdint>
#include <cstddef>

#define N_ 64
#define T_ 512
#define D_ 1024
#define H_ 1024
#define FH 4096  // 4*H
#define CH 64    // scan/gemm chunk length (timesteps)

typedef __attribute__((ext_vector_type(8))) short bf16x8;
typedef __attribute__((ext_vector_type(4))) float f32x4;

static __device__ __forceinline__ uint16_t f2bf_(float f) {
  union { float f; uint32_t u; } v; v.f = f;
  uint32_t u = v.u + 0x7FFFu + ((v.u >> 16) & 1u);
  return (uint16_t)(u >> 16);
}
static __device__ __forceinline__ float bf2f_(uint16_t s) {
  union { uint32_t u; float f; } v; v.u = ((uint32_t)s) << 16;
  return v.f;
}
// split u64 of two packed (hi:lo) elements into hi-pair / lo-pair u32s
static __device__ __forceinline__ void unpk2_(unsigned long long e,
                                              uint32_t& hi, uint32_t& lo) {
  uint32_t a = (uint32_t)e, b = (uint32_t)(e >> 32);
  hi = (a >> 16) | (b & 0xFFFF0000u);
  lo = (a & 0xFFFFu) | (b << 16);
}

#define ALD(p) (*(p))  // plain cacheable u64 load

// ---------------------------------------------------------------------------
// Pack W [1024][4096] into MFMA B-fragment order, split bf16 hi/lo (proven).
// ---------------------------------------------------------------------------
__global__ __launch_bounds__(256) void pack_w_k(const float* __restrict__ W,
                                                ushort* __restrict__ hi,
                                                ushort* __restrict__ lo) {
  const int i = blockIdx.x * 256 + threadIdx.x;  // 524288 = 256*32*64
  const int lane = i & 63, kc = (i >> 6) & 31, bid = i >> 11;
  const int c = lane & 15;
  const int col = (c >> 2) * H_ + (bid << 2) + (c & 3);
  const int k0 = (kc << 5) + ((lane >> 4) << 3);
  const size_t o = ((size_t)(bid * 32 + kc) * 64 + lane) * 8;
#pragma unroll
  for (int e = 0; e < 8; ++e) {
    float v = W[(size_t)(k0 + e) * FH + col];
    ushort h = f2bf_(v);
    hi[o + e] = h;
    lo[o + e] = f2bf_(v - bf2f_(h));
  }
}

// ---------------------------------------------------------------------------
// x: f32 -> bf16 hi/lo planes (r16-proven).
// ---------------------------------------------------------------------------
__global__ __launch_bounds__(256) void split_f32_k(const float* __restrict__ src,
                                                   ushort* __restrict__ hi,
                                                   ushort* __restrict__ lo) {
  const size_t i = (size_t)blockIdx.x * 256 + threadIdx.x;
  float4 v = reinterpret_cast<const float4*>(src)[i];
  ushort4 h, l;
  h.x = f2bf_(v.x); l.x = f2bf_(v.x - bf2f_(h.x));
  h.y = f2bf_(v.y); l.y = f2bf_(v.y - bf2f_(h.y));
  h.z = f2bf_(v.z); l.z = f2bf_(v.z - bf2f_(h.z));
  h.w = f2bf_(v.w); l.w = f2bf_(v.w - bf2f_(h.w));
  reinterpret_cast<ushort4*>(hi)[i] = h;
  reinterpret_cast<ushort4*>(lo)[i] = l;
}

// h0 f32 -> packed u32 (hi16:lo16); block 0 zeroes barrier flags + 8 release
// copies. 64 blocks x 256 thr x 4 elems (proven).
__global__ __launch_bounds__(256) void conv_h0pk_k(const float* __restrict__ src,
                                                   uint32_t* __restrict__ dst,
                                                   unsigned* bar) {
  if (blockIdx.x == 0) {
    bar[threadIdx.x] = 0u;                                  // flags[256]
    if (threadIdx.x < 8) bar[384 + 32 * threadIdx.x] = 0u;  // release copies
  }
  const int i = blockIdx.x * 256 + threadIdx.x;  // 16384 float4s
  float4 v = reinterpret_cast<const float4*>(src)[i];
  uint4 o;
  { ushort h = f2bf_(v.x); o.x = ((uint32_t)h << 16) | f2bf_(v.x - bf2f_(h)); }
  { ushort h = f2bf_(v.y); o.y = ((uint32_t)h << 16) | f2bf_(v.y - bf2f_(h)); }
  { ushort h = f2bf_(v.z); o.z = ((uint32_t)h << 16) | f2bf_(v.z - bf2f_(h)); }
  { ushort h = f2bf_(v.w); o.w = ((uint32_t)h << 16) | f2bf_(v.w - bf2f_(h)); }
  reinterpret_cast<uint4*>(dst)[i] = o;
}

// ---------------------------------------------------------------------------
// Shared GEMM body (r20 12-accumulator version, proven). r22: ALL streaming
// loads (x planes + Wx fragments) are NON-TEMPORAL — each line is read once
// per block, so skipping L2 allocation preserves the scan's hseq/xw L2
// residency (the r21 interference mechanism: GEMM streamed ~2 MB through
// each XCD L2, evicting lines shared by 32 scan blocks).
// ---------------------------------------------------------------------------
static __device__ __forceinline__ void gemm4_(
    const ushort* __restrict__ Wxh, const ushort* __restrict__ Wxl,
    const ushort* __restrict__ xh, const ushort* __restrict__ xl,
    const float* __restrict__ bias, uint32_t* __restrict__ xwp,
    int gbid, int tl, int t0, int lane, int mt) {
  const int row = (mt << 4) | (lane & 15);
  const int kg = lane >> 4;
  const bf16x8* Bh = reinterpret_cast<const bf16x8*>(Wxh) + (size_t)gbid * 2048 + lane;
  const bf16x8* Bl = reinterpret_cast<const bf16x8*>(Wxl) + (size_t)gbid * 2048 + lane;
  const ushort* ah = xh + ((size_t)row * T_ + t0) * D_ + (kg << 3);
  const ushort* al = xl + ((size_t)row * T_ + t0) * D_ + (kg << 3);

  f32x4 aA0 = {0.f,0.f,0.f,0.f}, aB0 = {0.f,0.f,0.f,0.f}, aC0 = {0.f,0.f,0.f,0.f};
  f32x4 aA1 = {0.f,0.f,0.f,0.f}, aB1 = {0.f,0.f,0.f,0.f}, aC1 = {0.f,0.f,0.f,0.f};
  f32x4 aA2 = {0.f,0.f,0.f,0.f}, aB2 = {0.f,0.f,0.f,0.f}, aC2 = {0.f,0.f,0.f,0.f};
  f32x4 aA3 = {0.f,0.f,0.f,0.f}, aB3 = {0.f,0.f,0.f,0.f}, aC3 = {0.f,0.f,0.f,0.f};
#pragma unroll 2
  for (int kc = 0; kc < 32; ++kc) {
    bf16x8 bh = __builtin_nontemporal_load(&Bh[kc << 6]);
    bf16x8 bl = __builtin_nontemporal_load(&Bl[kc << 6]);
    bf16x8 h0 = __builtin_nontemporal_load(
        reinterpret_cast<const bf16x8*>(ah + (kc << 5)));
    bf16x8 l0 = __builtin_nontemporal_load(
        reinterpret_cast<const bf16x8*>(al + (kc << 5)));
    bf16x8 h1 = __builtin_nontemporal_load(
        reinterpret_cast<const bf16x8*>(ah + D_ + (kc << 5)));
    bf16x8 l1 = __builtin_nontemporal_load(
        reinterpret_cast<const bf16x8*>(al + D_ + (kc << 5)));
    bf16x8 h2 = __builtin_nontemporal_load(
        reinterpret_cast<const bf16x8*>(ah + 2 * D_ + (kc << 5)));
    bf16x8 l2 = __builtin_nontemporal_load(
        reinterpret_cast<const bf16x8*>(al + 2 * D_ + (kc << 5)));
    bf16x8 h3 = __builtin_nontemporal_load(
        reinterpret_cast<const bf16x8*>(ah + 3 * D_ + (kc << 5)));
    bf16x8 l3 = __builtin_nontemporal_load(
        reinterpret_cast<const bf16x8*>(al + 3 * D_ + (kc << 5)));
    aA0 = __builtin_amdgcn_mfma_f32_16x16x32_bf16(h0, bh, aA0, 0, 0, 0);
    aA1 = __builtin_amdgcn_mfma_f32_16x16x32_bf16(h1, bh, aA1, 0, 0, 0);
    aA2 = __builtin_amdgcn_mfma_f32_16x16x32_bf16(h2, bh, aA2, 0, 0, 0);
    aA3 = __builtin_amdgcn_mfma_f32_16x16x32_bf16(h3, bh, aA3, 0, 0, 0);
    aB0 = __builtin_amdgcn_mfma_f32_16x16x32_bf16(h0, bl, aB0, 0, 0, 0);
    aB1 = __builtin_amdgcn_mfma_f32_16x16x32_bf16(h1, bl, aB1, 0, 0, 0);
    aB2 = __builtin_amdgcn_mfma_f32_16x16x32_bf16(h2, bl, aB2, 0, 0, 0);
    aB3 = __builtin_amdgcn_mfma_f32_16x16x32_bf16(h3, bl, aB3, 0, 0, 0);
    aC0 = __builtin_amdgcn_mfma_f32_16x16x32_bf16(l0, bh, aC0, 0, 0, 0);
    aC1 = __builtin_amdgcn_mfma_f32_16x16x32_bf16(l1, bh, aC1, 0, 0, 0);
    aC2 = __builtin_amdgcn_mfma_f32_16x16x32_bf16(l2, bh, aC2, 0, 0, 0);
    aC3 = __builtin_amdgcn_mfma_f32_16x16x32_bf16(l3, bh, aC3, 0, 0, 0);
  }
  f32x4 xa0 = (aA0 + aB0) + aC0;
  f32x4 xa1 = (aA1 + aB1) + aC1;
  f32x4 xa2 = (aA2 + aB2) + aC2;
  f32x4 xa3 = (aA3 + aB3) + aC3;

  // D layout (m89-verified): col = lane&15, row = (lane>>4)*4 + r
  const int dc = lane & 15, dr = (lane >> 4) << 2;
  const int g = dc >> 2, jj = dc & 3;
  const float bv = bias[g * H_ + (gbid << 2) + jj];
#pragma unroll
  for (int r = 0; r < 4; ++r) {
    const int rw = (mt << 4) + dr + r;
    const size_t o = ((size_t)tl * 256 + gbid) * 1024 + rw * 16 + jj * 4 + g;
    float v0 = xa0[r] + bv, v1 = xa1[r] + bv, v2 = xa2[r] + bv, v3 = xa3[r] + bv;
    ushort h;
    h = f2bf_(v0); xwp[o] = ((uint32_t)h << 16) | f2bf_(v0 - bf2f_(h));
    h = f2bf_(v1); xwp[o + 262144] = ((uint32_t)h << 16) | f2bf_(v1 - bf2f_(h));
    h = f2bf_(v2); xwp[o + 2 * 262144] = ((uint32_t)h << 16) | f2bf_(v2 - bf2f_(h));
    h = f2bf_(v3); xwp[o + 3 * 262144] = ((uint32_t)h << 16) | f2bf_(v3 - bf2f_(h));
  }
}

// Standalone GEMM for chunk 0 (CH=64 steps). Grid dim3(16, 256), 4 waves.
__global__ __launch_bounds__(256, 3) void gemm_xw_mfma(
    const ushort* __restrict__ Wxh, const ushort* __restrict__ Wxl,
    const ushort* __restrict__ xh, const ushort* __restrict__ xl,
    const float* __restrict__ bias, uint32_t* __restrict__ xwp, int tb) {
  const int tl = blockIdx.x << 2;
  gemm4_(Wxh, Wxl, xh, xl, bias, xwp, blockIdx.y, tl, tb + tl,
         threadIdx.x & 63, threadIdx.x >> 6);
}

// ---------------------------------------------------------------------------
// FUSED dispatch (r21-proven, r22 tweaks): 512 blocks, 2 roles.
//  blocks 0..255   : persistent scan of CH=64 steps; r22: scan waves run at
//                    s_setprio(1) (T5 regime: role-split co-resident waves)
//                    so the latency-critical chain wins issue arbitration.
//  blocks 256..511 : GEMM for next chunk (non-temporal streams, prio 0).
// Co-residency exact: LDS 74.2KB x 2/CU; launch_bounds(512,4) caps VGPR<=128.
// ---------------------------------------------------------------------------
__global__ __launch_bounds__(512, 4) void lstm_fused_k(
    const ushort* __restrict__ Whh_g, const ushort* __restrict__ Whl_g,
    const ushort* __restrict__ Wxh, const ushort* __restrict__ Wxl,
    const ushort* __restrict__ xh, const ushort* __restrict__ xl,
    const float* __restrict__ bias,
    const uint32_t* __restrict__ xw_cur, uint32_t* __restrict__ xw_nxt,
    uint32_t* __restrict__ hseq, float* __restrict__ cbuf,
    float* __restrict__ out, unsigned* __restrict__ bar, int tb) {
  extern __shared__ char ldsraw[];
  const int tid = threadIdx.x;
  const int lane = tid & 63, w = tid >> 6;

  if (blockIdx.x >= 256) {
    // ---- GEMM role: next chunk [tb+CH, tb+2*CH) at default (low) prio ----
    const int tbn = tb + CH;
    if (tbn >= T_) return;
    const int gbid = blockIdx.x - 256;
    const int mt = w & 3, sub = w >> 2;
#pragma unroll 1
    for (int tg = 0; tg < 8; ++tg) {
      const int tl = (tg << 3) + (sub << 2);
      gemm4_(Wxh, Wxl, xh, xl, bias, xw_nxt, gbid, tl, tbn + tl, lane, mt);
    }
    return;
  }

  // ---- scan role: elevated wave priority (r22) ----
  __builtin_amdgcn_s_setprio(1);

  bf16x8* const WhH = (bf16x8*)ldsraw;       // 2048 units (32 KB)
  bf16x8* const WhL = WhH + 2048;            // 2048 units (32 KB)
  float* const pre = (float*)(WhL + 2048);   // 128*17 floats (8704 B)

  const int bid = blockIdx.x;
  const int mt = w & 3, kh = w >> 2;
  const int khb = kh << 4;
  const int arow = (mt << 4) | (lane & 15);
  const int kg = lane >> 4;
  const int dc = lane & 15, dr = (lane >> 4) << 2;
  const int en = tid >> 2, ejj = tid & 3;

  unsigned* const relmy = bar + 384 + ((bid & 7) << 5);

  // one-time Wh stage into LDS (identity copy of packed layout)
  {
    const bf16x8* gh = reinterpret_cast<const bf16x8*>(Whh_g) + (size_t)bid * 2048;
    const bf16x8* gl = reinterpret_cast<const bf16x8*>(Whl_g) + (size_t)bid * 2048;
#pragma unroll
    for (int r = 0; r < 4; ++r) {
      int u = tid + (r << 9);
      WhH[u] = gh[u];
      WhL[u] = gl[u];
    }
  }
  __syncthreads();

  for (int tl = 0; tl < CH; ++tl) {
    const int t = tb + tl;
    f32x4 acc0 = {0.f, 0.f, 0.f, 0.f};
    f32x4 acc1 = {0.f, 0.f, 0.f, 0.f};
    const unsigned long long* Apk =
        (const unsigned long long*)(hseq + (size_t)t * 65536) +
        arow * 512 + (kh << 8) + kg * 4;

    unsigned long long pa0, pa1, pa2, pa3, pb0, pb1, pb2, pb3;
    unsigned long long pc0, pc1, pc2, pc3, pd0, pd1, pd2, pd3;
    unsigned long long qa0, qa1, qa2, qa3, qb0, qb1, qb2, qb3;
    unsigned long long qc0, qc1, qc2, qc3, qd0, qd1, qd2, qd3;

#define HLD(P, CHk)                                                           \
  {                                                                           \
    const unsigned long long* ap_ = Apk + ((CHk) << 6);                       \
    P##a0 = ALD(ap_ + 0);  P##a1 = ALD(ap_ + 1);                              \
    P##a2 = ALD(ap_ + 2);  P##a3 = ALD(ap_ + 3);                              \
    P##b0 = ALD(ap_ + 16); P##b1 = ALD(ap_ + 17);                             \
    P##b2 = ALD(ap_ + 18); P##b3 = ALD(ap_ + 19);                             \
    P##c0 = ALD(ap_ + 32); P##c1 = ALD(ap_ + 33);                             \
    P##c2 = ALD(ap_ + 34); P##c3 = ALD(ap_ + 35);                             \
    P##d0 = ALD(ap_ + 48); P##d1 = ALD(ap_ + 49);                             \
    P##d2 = ALD(ap_ + 50); P##d3 = ALD(ap_ + 51);                             \
  }

#define HKC(E0, E1, E2, E3, KCG, ACC)                                         \
  {                                                                           \
    union { uint32_t u[4]; bf16x8 v; } fh_, fl_;                              \
    unpk2_(E0, fh_.u[0], fl_.u[0]);                                           \
    unpk2_(E1, fh_.u[1], fl_.u[1]);                                           \
    unpk2_(E2, fh_.u[2], fl_.u[2]);                                           \
    unpk2_(E3, fh_.u[3], fl_.u[3]);                                           \
    bf16x8 bh_ = WhH[((KCG) << 6) + lane];                                    \
    bf16x8 bl_ = WhL[((KCG) << 6) + lane];                                    \
    ACC = __builtin_amdgcn_mfma_f32_16x16x32_bf16(fh_.v, bh_, ACC, 0, 0, 0);  \
    ACC = __builtin_amdgcn_mfma_f32_16x16x32_bf16(fh_.v, bl_, ACC, 0, 0, 0);  \
    ACC = __builtin_amdgcn_mfma_f32_16x16x32_bf16(fl_.v, bh_, ACC, 0, 0, 0);  \
  }

#define HCOMP(P, CHk)                                                         \
  HKC(P##a0, P##a1, P##a2, P##a3, khb + (CHk) * 4 + 0, acc0)                  \
  HKC(P##b0, P##b1, P##b2, P##b3, khb + (CHk) * 4 + 1, acc1)                  \
  HKC(P##c0, P##c1, P##c2, P##c3, khb + (CHk) * 4 + 2, acc0)                  \
  HKC(P##d0, P##d1, P##d2, P##d3, khb + (CHk) * 4 + 3, acc1)

    HLD(p, 0)
    HLD(q, 1) HCOMP(p, 0)
    HLD(p, 2) HCOMP(q, 1)
    HLD(q, 3) HCOMP(p, 2)
    HCOMP(q, 3)
#undef HLD
#undef HKC
#undef HCOMP

    f32x4 accs = acc0 + acc1;
#pragma unroll
    for (int r = 0; r < 4; ++r)
      pre[((kh << 6) + (mt << 4) + dr + r) * 17 + dc] = accs[r];
    __syncthreads();

    if (tid < 256) {
      const uint4 xp = *reinterpret_cast<const uint4*>(
          xw_cur + (size_t)tl * 262144 + (size_t)bid * 1024 + en * 16 + ejj * 4);
      float a0 = pre[en * 17 + ejj] + pre[(64 + en) * 17 + ejj] +
                 bf2f_((ushort)(xp.x >> 16)) + bf2f_((ushort)(xp.x & 0xFFFF));
      float a1 = pre[en * 17 + 4 + ejj] + pre[(64 + en) * 17 + 4 + ejj] +
                 bf2f_((ushort)(xp.y >> 16)) + bf2f_((ushort)(xp.y & 0xFFFF));
      float a2 = pre[en * 17 + 8 + ejj] + pre[(64 + en) * 17 + 8 + ejj] +
                 bf2f_((ushort)(xp.z >> 16)) + bf2f_((ushort)(xp.z & 0xFFFF));
      float a3 = pre[en * 17 + 12 + ejj] + pre[(64 + en) * 17 + 12 + ejj] +
                 bf2f_((ushort)(xp.w >> 16)) + bf2f_((ushort)(xp.w & 0xFFFF));
      const int hx = en * H_ + (bid << 2) + ejj;
      float cp = (t == 0) ? 0.f : cbuf[hx];
      float iv = 1.f / (1.f + __expf(-a0));
      float fv = 1.f / (1.f + __expf(-a1));
      float ov = 1.f / (1.f + __expf(-a2));
      float gv = tanhf(a3);
      float cn = fmaf(fv, cp, iv * gv);
      cbuf[hx] = cn;
      float hn = ov * tanhf(cn);
      out[(size_t)en * ((size_t)T_ * H_) + (size_t)t * H_ + (bid << 2) + ejj] = hn;
      ushort hh = f2bf_(hn);
      uint32_t pk = ((uint32_t)hh << 16) | f2bf_(hn - bf2f_(hh));
      __hip_atomic_store(&hseq[(size_t)(t + 1) * 65536 + hx], pk,
                         __ATOMIC_RELAXED, __HIP_MEMORY_SCOPE_AGENT);
    }

    asm volatile("s_waitcnt vmcnt(0)" ::: "memory");
    __syncthreads();

    const unsigned tgt = (unsigned)(t + 1);
    if (tid == 0)
      __hip_atomic_store(&bar[bid], tgt, __ATOMIC_RELAXED,
                         __HIP_MEMORY_SCOPE_AGENT);
    if (bid == 0 && tid < 64) {
      const unsigned long long* fl = (const unsigned long long*)bar;
      for (;;) {
        unsigned long long v0 = __hip_atomic_load(fl + tid, __ATOMIC_RELAXED,
                                                  __HIP_MEMORY_SCOPE_AGENT);
        unsigned long long v1 = __hip_atomic_load(fl + 64 + tid, __ATOMIC_RELAXED,
                                                  __HIP_MEMORY_SCOPE_AGENT);
        bool ok = ((unsigned)v0 >= tgt) && ((unsigned)(v0 >> 32) >= tgt) &&
                  ((unsigned)v1 >= tgt) && ((unsigned)(v1 >> 32) >= tgt);
        if (__all((int)ok)) break;
      }
      if (tid < 8)
        __hip_atomic_store(bar + 384 + (tid << 5), tgt, __ATOMIC_RELAXED,
                           __HIP_MEMORY_SCOPE_AGENT);
    }
    if (tid == 0) {
      while (__hip_atomic_load(relmy, __ATOMIC_RELAXED,
                               __HIP_MEMORY_SCOPE_AGENT) < tgt)
        __builtin_amdgcn_s_sleep(1);
    }
    __syncthreads();
  }
}

// ---------------------------------------------------------------------------
// Fallback (tiny ws): fused per-step VALU kernel (round-1 proven). Slow.
// ---------------------------------------------------------------------------
__global__ __launch_bounds__(256) void lstm_step_fb(
    const float* __restrict__ xt, const float* __restrict__ Wx,
    const float* __restrict__ Wh, const float* __restrict__ bias,
    const float* __restrict__ h_prev, long long hstride,
    float* __restrict__ cbuf, float* __restrict__ h_out, int first) {
  __shared__ float hS[32][128];
  __shared__ float wT[32][132];
  __shared__ float pre[32][34];
  const int tid = threadIdx.x;
  const int colblk = blockIdx.x & 127;
  const int nh = blockIdx.x >> 7;
  const int j0 = colblk << 3;
  const int n0 = nh << 5;
  const int ng = tid >> 4, cg2 = tid & 15;
  const int na = ng << 1, ca = cg2 << 1;

  float acc[2][2] = {{0.f, 0.f}, {0.f, 0.f}};

#pragma unroll
  for (int pr = 0; pr < 2; ++pr) {
    const float* src = (pr == 0) ? h_prev : xt;
    long long sstr = (pr == 0) ? hstride : (long long)T_ * D_;
    const float* W = (pr == 0) ? Wh : Wx;
    for (int k0 = 0; k0 < 1024; k0 += 128) {
      __syncthreads();
#pragma unroll
      for (int p = 0; p < 4; ++p) {
        int idx = tid + (p << 8);
        int r = idx >> 5, c4 = (idx & 31) << 2;
        *reinterpret_cast<float4*>(&hS[r][c4]) =
            *reinterpret_cast<const float4*>(src + (size_t)(n0 + r) * sstr + k0 + c4);
      }
#pragma unroll
      for (int p = 0; p < 4; ++p) {
        int idx = tid + (p << 8);
        int k = idx >> 3, sub = idx & 7;
        int g = sub >> 1, hf = (sub & 1) << 2;
        float4 v = *reinterpret_cast<const float4*>(
            W + (size_t)(k0 + k) * FH + g * H_ + j0 + hf);
        int cb = (g << 3) + hf;
        wT[cb][k] = v.x; wT[cb + 1][k] = v.y; wT[cb + 2][k] = v.z; wT[cb + 3][k] = v.w;
      }
      __syncthreads();
#pragma unroll
      for (int kk = 0; kk < 128; kk += 4) {
        float4 h0v = *reinterpret_cast<const float4*>(&hS[na][kk]);
        float4 h1v = *reinterpret_cast<const float4*>(&hS[na + 1][kk]);
        float4 w0 = *reinterpret_cast<const float4*>(&wT[ca][kk]);
        float4 w1 = *reinterpret_cast<const float4*>(&wT[ca + 1][kk]);
        acc[0][0] = fmaf(h0v.x, w0.x, acc[0][0]); acc[0][0] = fmaf(h0v.y, w0.y, acc[0][0]);
        acc[0][0] = fmaf(h0v.z, w0.z, acc[0][0]); acc[0][0] = fmaf(h0v.w, w0.w, acc[0][0]);
        acc[0][1] = fmaf(h0v.x, w1.x, acc[0][1]); acc[0][1] = fmaf(h0v.y, w1.y, acc[0][1]);
        acc[0][1] = fmaf(h0v.z, w1.z, acc[0][1]); acc[0][1] = fmaf(h0v.w, w1.w, acc[0][1]);
        acc[1][0] = fmaf(h1v.x, w0.x, acc[1][0]); acc[1][0] = fmaf(h1v.y, w0.y, acc[1][0]);
        acc[1][0] = fmaf(h1v.z, w0.z, acc[1][0]); acc[1][0] = fmaf(h1v.w, w0.w, acc[1][0]);
        acc[1][1] = fmaf(h1v.x, w1.x, acc[1][1]); acc[1][1] = fmaf(h1v.y, w1.y, acc[1][1]);
        acc[1][1] = fmaf(h1v.z, w1.z, acc[1][1]); acc[1][1] = fmaf(h1v.w, w1.w, acc[1][1]);
      }
    }
  }

  pre[na][ca] = acc[0][0];
  pre[na][ca + 1] = acc[0][1];
  pre[na + 1][ca] = acc[1][0];
  pre[na + 1][ca + 1] = acc[1][1];
  __syncthreads();

  const int nl = tid >> 3, jl = tid & 7;
  const int n = n0 + nl;
  const int jg = j0 + jl;
  float ai = pre[nl][jl] + bias[jg];
  float af = pre[nl][8 + jl] + bias[H_ + jg];
  float ao = pre[nl][16 + jl] + bias[2 * H_ + jg];
  float ag = pre[nl][24 + jl] + bias[3 * H_ + jg];
  float cp = first ? 0.0f : cbuf[n * H_ + jg];
  float iv = 1.f / (1.f + __expf(-ai));
  float fv = 1.f / (1.f + __expf(-af));
  float ov = 1.f / (1.f + __expf(-ao));
  float gv = tanhf(ag);
  float cn = fmaf(fv, cp, iv * gv);
  cbuf[n * H_ + jg] = cn;
  h_out[(size_t)n * ((size_t)T_ * H_) + jg] = ov * tanhf(cn);
}

// ---------------------------------------------------------------------------
extern "C" void kernel_launch(void* const* d_in, const int* in_sizes, int n_in,
                              void* d_out, int out_size, void* d_ws, size_t ws_size,
                              hipStream_t stream) {
  (void)in_sizes; (void)n_in; (void)out_size;
  const float* x  = (const float*)d_in[0];
  const float* h0 = (const float*)d_in[1];
  const float* Wx = (const float*)d_in[2];
  const float* Wh = (const float*)d_in[3];
  const float* b  = (const float*)d_in[4];
  float* out = (float*)d_out;

  const size_t MB = 1u << 20;
  char* p = (char*)d_ws;

  if (ws_size >= 420 * MB) {
    unsigned* bar = (unsigned*)p;                // flags[256] + rel copies @+384
    ushort* Whh = (ushort*)(p + 1 * MB);
    ushort* Whl = (ushort*)(p + 9 * MB);
    ushort* Wxh = (ushort*)(p + 17 * MB);
    ushort* Wxl = (ushort*)(p + 25 * MB);
    uint32_t* hseq = (uint32_t*)(p + 33 * MB);   // 513 * 256 KB ≈ 128.25 MB
    float* cbuf = (float*)(p + 162 * MB);        // 256 KB
    ushort* xh = (ushort*)(p + 163 * MB);        // 64 MB
    ushort* xl = (ushort*)(p + 227 * MB);        // 64 MB
    uint32_t* xwp0 = (uint32_t*)(p + 291 * MB);  // 64 MB
    uint32_t* xwp1 = (uint32_t*)(p + 355 * MB);  // 64 MB (ends 419 MB)

    pack_w_k<<<dim3(2048), dim3(256), 0, stream>>>(Wh, Whh, Whl);
    pack_w_k<<<dim3(2048), dim3(256), 0, stream>>>(Wx, Wxh, Wxl);
    split_f32_k<<<dim3(32768), dim3(256), 0, stream>>>(x, xh, xl);
    conv_h0pk_k<<<dim3(64), dim3(256), 0, stream>>>(h0, hseq, bar);

    const unsigned SH = 2048 * 16 * 2 + 128 * 17 * 4;  // 74240 B
    hipFuncSetAttribute((const void*)lstm_fused_k,
                        hipFuncAttributeMaxDynamicSharedMemorySize, (int)SH);

    // chunk 0's xw via standalone GEMM, then 8 fused scan+next-gemm dispatches
    gemm_xw_mfma<<<dim3(16, 256), dim3(256), 0, stream>>>(Wxh, Wxl, xh, xl, b,
                                                          xwp0, 0);
    for (int c = 0; c < 8; ++c) {
      uint32_t* cur = (c & 1) ? xwp1 : xwp0;
      uint32_t* nxt = (c & 1) ? xwp0 : xwp1;
      lstm_fused_k<<<dim3(512), dim3(512), SH, stream>>>(
          Whh, Whl, Wxh, Wxl, xh, xl, b, cur, nxt, hseq, cbuf, out, bar,
          c * CH);
    }
  } else {
    float* cbuf = (float*)p;  // 256 KB
    for (int t = 0; t < T_; ++t) {
      const float* hp = (t == 0) ? h0 : out + (size_t)(t - 1) * H_;
      long long hstr = (t == 0) ? (long long)H_ : (long long)T_ * H_;
      lstm_step_fb<<<dim3(256), dim3(256), 0, stream>>>(
          x + (size_t)t * D_, Wx, Wh, b, hp, hstr, cbuf,
          out + (size_t)t * H_, t == 0);
    }
  }
}

// Round 23
// 8003.422 us; speedup vs baseline: 1.2840x; 1.2840x over previous
//
#include <hip/hip_runtime.h>
#include <cstdint>
#include <cstddef>

#define N_ 64
#define T_ 512
#define D_ 1024
#define H_ 1024
#define FH 4096  // 4*H
#define CH 64    // scan/gemm chunk length (timesteps)

typedef __attribute__((ext_vector_type(8))) short bf16x8;
typedef __attribute__((ext_vector_type(4))) float f32x4;

static __device__ __forceinline__ uint16_t f2bf_(float f) {
  union { float f; uint32_t u; } v; v.f = f;
  uint32_t u = v.u + 0x7FFFu + ((v.u >> 16) & 1u);
  return (uint16_t)(u >> 16);
}
static __device__ __forceinline__ float bf2f_(uint16_t s) {
  union { uint32_t u; float f; } v; v.u = ((uint32_t)s) << 16;
  return v.f;
}
// split u64 of two packed (hi:lo) elements into hi-pair / lo-pair u32s
static __device__ __forceinline__ void unpk2_(unsigned long long e,
                                              uint32_t& hi, uint32_t& lo) {
  uint32_t a = (uint32_t)e, b = (uint32_t)(e >> 32);
  hi = (a >> 16) | (b & 0xFFFF0000u);
  lo = (a & 0xFFFFu) | (b << 16);
}

#define ALD(p) (*(p))  // plain cacheable u64 load

// ---------------------------------------------------------------------------
// Pack W [1024][4096] into MFMA B-fragment order, split bf16 hi/lo (proven).
// ---------------------------------------------------------------------------
__global__ __launch_bounds__(256) void pack_w_k(const float* __restrict__ W,
                                                ushort* __restrict__ hi,
                                                ushort* __restrict__ lo) {
  const int i = blockIdx.x * 256 + threadIdx.x;  // 524288 = 256*32*64
  const int lane = i & 63, kc = (i >> 6) & 31, bid = i >> 11;
  const int c = lane & 15;
  const int col = (c >> 2) * H_ + (bid << 2) + (c & 3);
  const int k0 = (kc << 5) + ((lane >> 4) << 3);
  const size_t o = ((size_t)(bid * 32 + kc) * 64 + lane) * 8;
#pragma unroll
  for (int e = 0; e < 8; ++e) {
    float v = W[(size_t)(k0 + e) * FH + col];
    ushort h = f2bf_(v);
    hi[o + e] = h;
    lo[o + e] = f2bf_(v - bf2f_(h));
  }
}

// ---------------------------------------------------------------------------
// x: f32 -> bf16 hi/lo planes (r16-proven).
// ---------------------------------------------------------------------------
__global__ __launch_bounds__(256) void split_f32_k(const float* __restrict__ src,
                                                   ushort* __restrict__ hi,
                                                   ushort* __restrict__ lo) {
  const size_t i = (size_t)blockIdx.x * 256 + threadIdx.x;
  float4 v = reinterpret_cast<const float4*>(src)[i];
  ushort4 h, l;
  h.x = f2bf_(v.x); l.x = f2bf_(v.x - bf2f_(h.x));
  h.y = f2bf_(v.y); l.y = f2bf_(v.y - bf2f_(h.y));
  h.z = f2bf_(v.z); l.z = f2bf_(v.z - bf2f_(h.z));
  h.w = f2bf_(v.w); l.w = f2bf_(v.w - bf2f_(h.w));
  reinterpret_cast<ushort4*>(hi)[i] = h;
  reinterpret_cast<ushort4*>(lo)[i] = l;
}

// h0 f32 -> packed u32 (hi16:lo16); block 0 zeroes barrier flags + 8 release
// copies. 64 blocks x 256 thr x 4 elems (proven).
__global__ __launch_bounds__(256) void conv_h0pk_k(const float* __restrict__ src,
                                                   uint32_t* __restrict__ dst,
                                                   unsigned* bar) {
  if (blockIdx.x == 0) {
    bar[threadIdx.x] = 0u;                                  // flags[256]
    if (threadIdx.x < 8) bar[384 + 32 * threadIdx.x] = 0u;  // release copies
  }
  const int i = blockIdx.x * 256 + threadIdx.x;  // 16384 float4s
  float4 v = reinterpret_cast<const float4*>(src)[i];
  uint4 o;
  { ushort h = f2bf_(v.x); o.x = ((uint32_t)h << 16) | f2bf_(v.x - bf2f_(h)); }
  { ushort h = f2bf_(v.y); o.y = ((uint32_t)h << 16) | f2bf_(v.y - bf2f_(h)); }
  { ushort h = f2bf_(v.z); o.z = ((uint32_t)h << 16) | f2bf_(v.z - bf2f_(h)); }
  { ushort h = f2bf_(v.w); o.w = ((uint32_t)h << 16) | f2bf_(v.w - bf2f_(h)); }
  reinterpret_cast<uint4*>(dst)[i] = o;
}

// ---------------------------------------------------------------------------
// Shared GEMM body: computes xw for 4 timesteps (t0..t0+3) for gate-col block
// gbid; writes u32-packed hi:lo at chunk-local base tl. r20 12-accumulator
// version. PLAIN CACHEABLE loads (r22's non-temporal variant tripled FETCH —
// the L2 was absorbing 8x B re-reads and 256x A replication; reverted).
// ---------------------------------------------------------------------------
static __device__ __forceinline__ void gemm4_(
    const ushort* __restrict__ Wxh, const ushort* __restrict__ Wxl,
    const ushort* __restrict__ xh, const ushort* __restrict__ xl,
    const float* __restrict__ bias, uint32_t* __restrict__ xwp,
    int gbid, int tl, int t0, int lane, int mt) {
  const int row = (mt << 4) | (lane & 15);
  const int kg = lane >> 4;
  const bf16x8* Bh = reinterpret_cast<const bf16x8*>(Wxh) + (size_t)gbid * 2048 + lane;
  const bf16x8* Bl = reinterpret_cast<const bf16x8*>(Wxl) + (size_t)gbid * 2048 + lane;
  const ushort* ah = xh + ((size_t)row * T_ + t0) * D_ + (kg << 3);
  const ushort* al = xl + ((size_t)row * T_ + t0) * D_ + (kg << 3);

  f32x4 aA0 = {0.f,0.f,0.f,0.f}, aB0 = {0.f,0.f,0.f,0.f}, aC0 = {0.f,0.f,0.f,0.f};
  f32x4 aA1 = {0.f,0.f,0.f,0.f}, aB1 = {0.f,0.f,0.f,0.f}, aC1 = {0.f,0.f,0.f,0.f};
  f32x4 aA2 = {0.f,0.f,0.f,0.f}, aB2 = {0.f,0.f,0.f,0.f}, aC2 = {0.f,0.f,0.f,0.f};
  f32x4 aA3 = {0.f,0.f,0.f,0.f}, aB3 = {0.f,0.f,0.f,0.f}, aC3 = {0.f,0.f,0.f,0.f};
#pragma unroll 2
  for (int kc = 0; kc < 32; ++kc) {
    bf16x8 bh = Bh[kc << 6];
    bf16x8 bl = Bl[kc << 6];
    bf16x8 h0 = *reinterpret_cast<const bf16x8*>(ah + (kc << 5));
    bf16x8 l0 = *reinterpret_cast<const bf16x8*>(al + (kc << 5));
    bf16x8 h1 = *reinterpret_cast<const bf16x8*>(ah + D_ + (kc << 5));
    bf16x8 l1 = *reinterpret_cast<const bf16x8*>(al + D_ + (kc << 5));
    bf16x8 h2 = *reinterpret_cast<const bf16x8*>(ah + 2 * D_ + (kc << 5));
    bf16x8 l2 = *reinterpret_cast<const bf16x8*>(al + 2 * D_ + (kc << 5));
    bf16x8 h3 = *reinterpret_cast<const bf16x8*>(ah + 3 * D_ + (kc << 5));
    bf16x8 l3 = *reinterpret_cast<const bf16x8*>(al + 3 * D_ + (kc << 5));
    aA0 = __builtin_amdgcn_mfma_f32_16x16x32_bf16(h0, bh, aA0, 0, 0, 0);
    aA1 = __builtin_amdgcn_mfma_f32_16x16x32_bf16(h1, bh, aA1, 0, 0, 0);
    aA2 = __builtin_amdgcn_mfma_f32_16x16x32_bf16(h2, bh, aA2, 0, 0, 0);
    aA3 = __builtin_amdgcn_mfma_f32_16x16x32_bf16(h3, bh, aA3, 0, 0, 0);
    aB0 = __builtin_amdgcn_mfma_f32_16x16x32_bf16(h0, bl, aB0, 0, 0, 0);
    aB1 = __builtin_amdgcn_mfma_f32_16x16x32_bf16(h1, bl, aB1, 0, 0, 0);
    aB2 = __builtin_amdgcn_mfma_f32_16x16x32_bf16(h2, bl, aB2, 0, 0, 0);
    aB3 = __builtin_amdgcn_mfma_f32_16x16x32_bf16(h3, bl, aB3, 0, 0, 0);
    aC0 = __builtin_amdgcn_mfma_f32_16x16x32_bf16(l0, bh, aC0, 0, 0, 0);
    aC1 = __builtin_amdgcn_mfma_f32_16x16x32_bf16(l1, bh, aC1, 0, 0, 0);
    aC2 = __builtin_amdgcn_mfma_f32_16x16x32_bf16(l2, bh, aC2, 0, 0, 0);
    aC3 = __builtin_amdgcn_mfma_f32_16x16x32_bf16(l3, bh, aC3, 0, 0, 0);
  }
  f32x4 xa0 = (aA0 + aB0) + aC0;
  f32x4 xa1 = (aA1 + aB1) + aC1;
  f32x4 xa2 = (aA2 + aB2) + aC2;
  f32x4 xa3 = (aA3 + aB3) + aC3;

  // D layout (m89-verified): col = lane&15, row = (lane>>4)*4 + r
  const int dc = lane & 15, dr = (lane >> 4) << 2;
  const int g = dc >> 2, jj = dc & 3;
  const float bv = bias[g * H_ + (gbid << 2) + jj];
#pragma unroll
  for (int r = 0; r < 4; ++r) {
    const int rw = (mt << 4) + dr + r;
    const size_t o = ((size_t)tl * 256 + gbid) * 1024 + rw * 16 + jj * 4 + g;
    float v0 = xa0[r] + bv, v1 = xa1[r] + bv, v2 = xa2[r] + bv, v3 = xa3[r] + bv;
    ushort h;
    h = f2bf_(v0); xwp[o] = ((uint32_t)h << 16) | f2bf_(v0 - bf2f_(h));
    h = f2bf_(v1); xwp[o + 262144] = ((uint32_t)h << 16) | f2bf_(v1 - bf2f_(h));
    h = f2bf_(v2); xwp[o + 2 * 262144] = ((uint32_t)h << 16) | f2bf_(v2 - bf2f_(h));
    h = f2bf_(v3); xwp[o + 3 * 262144] = ((uint32_t)h << 16) | f2bf_(v3 - bf2f_(h));
  }
}

// Standalone GEMM for chunk 0 (CH=64 steps). Grid dim3(16, 256), 4 waves.
__global__ __launch_bounds__(256, 3) void gemm_xw_mfma(
    const ushort* __restrict__ Wxh, const ushort* __restrict__ Wxl,
    const ushort* __restrict__ xh, const ushort* __restrict__ xl,
    const float* __restrict__ bias, uint32_t* __restrict__ xwp, int tb) {
  const int tl = blockIdx.x << 2;
  gemm4_(Wxh, Wxl, xh, xl, bias, xwp, blockIdx.y, tl, tb + tl,
         threadIdx.x & 63, threadIdx.x >> 6);
}

// ---------------------------------------------------------------------------
// FUSED dispatch (r21-proven, 8.05 ms config — exact revert of r22):
//  blocks 0..255   : persistent scan of CH=64 steps [tb,tb+64).
//  blocks 256..511 : GEMM for the NEXT chunk's xw (plain cacheable loads).
// Co-residency exact: LDS 74.2KB x 2/CU; launch_bounds(512,4) caps VGPR<=128.
// ---------------------------------------------------------------------------
__global__ __launch_bounds__(512, 4) void lstm_fused_k(
    const ushort* __restrict__ Whh_g, const ushort* __restrict__ Whl_g,
    const ushort* __restrict__ Wxh, const ushort* __restrict__ Wxl,
    const ushort* __restrict__ xh, const ushort* __restrict__ xl,
    const float* __restrict__ bias,
    const uint32_t* __restrict__ xw_cur, uint32_t* __restrict__ xw_nxt,
    uint32_t* __restrict__ hseq, float* __restrict__ cbuf,
    float* __restrict__ out, unsigned* __restrict__ bar, int tb) {
  extern __shared__ char ldsraw[];
  const int tid = threadIdx.x;
  const int lane = tid & 63, w = tid >> 6;

  if (blockIdx.x >= 256) {
    // ---- GEMM role: next chunk [tb+CH, tb+2*CH) ----
    const int tbn = tb + CH;
    if (tbn >= T_) return;
    const int gbid = blockIdx.x - 256;
    const int mt = w & 3, sub = w >> 2;
#pragma unroll 1
    for (int tg = 0; tg < 8; ++tg) {
      const int tl = (tg << 3) + (sub << 2);
      gemm4_(Wxh, Wxl, xh, xl, bias, xw_nxt, gbid, tl, tbn + tl, lane, mt);
    }
    return;
  }

  // ---- scan role (verbatim r19/r20 body, CH-step loop) ----
  bf16x8* const WhH = (bf16x8*)ldsraw;       // 2048 units (32 KB)
  bf16x8* const WhL = WhH + 2048;            // 2048 units (32 KB)
  float* const pre = (float*)(WhL + 2048);   // 128*17 floats (8704 B)

  const int bid = blockIdx.x;
  const int mt = w & 3, kh = w >> 2;
  const int khb = kh << 4;
  const int arow = (mt << 4) | (lane & 15);
  const int kg = lane >> 4;
  const int dc = lane & 15, dr = (lane >> 4) << 2;
  const int en = tid >> 2, ejj = tid & 3;

  unsigned* const relmy = bar + 384 + ((bid & 7) << 5);

  // one-time Wh stage into LDS (identity copy of packed layout)
  {
    const bf16x8* gh = reinterpret_cast<const bf16x8*>(Whh_g) + (size_t)bid * 2048;
    const bf16x8* gl = reinterpret_cast<const bf16x8*>(Whl_g) + (size_t)bid * 2048;
#pragma unroll
    for (int r = 0; r < 4; ++r) {
      int u = tid + (r << 9);
      WhH[u] = gh[u];
      WhL[u] = gl[u];
    }
  }
  __syncthreads();

  for (int tl = 0; tl < CH; ++tl) {
    const int t = tb + tl;
    f32x4 acc0 = {0.f, 0.f, 0.f, 0.f};
    f32x4 acc1 = {0.f, 0.f, 0.f, 0.f};
    const unsigned long long* Apk =
        (const unsigned long long*)(hseq + (size_t)t * 65536) +
        arow * 512 + (kh << 8) + kg * 4;

    unsigned long long pa0, pa1, pa2, pa3, pb0, pb1, pb2, pb3;
    unsigned long long pc0, pc1, pc2, pc3, pd0, pd1, pd2, pd3;
    unsigned long long qa0, qa1, qa2, qa3, qb0, qb1, qb2, qb3;
    unsigned long long qc0, qc1, qc2, qc3, qd0, qd1, qd2, qd3;

#define HLD(P, CHk)                                                           \
  {                                                                           \
    const unsigned long long* ap_ = Apk + ((CHk) << 6);                       \
    P##a0 = ALD(ap_ + 0);  P##a1 = ALD(ap_ + 1);                              \
    P##a2 = ALD(ap_ + 2);  P##a3 = ALD(ap_ + 3);                              \
    P##b0 = ALD(ap_ + 16); P##b1 = ALD(ap_ + 17);                             \
    P##b2 = ALD(ap_ + 18); P##b3 = ALD(ap_ + 19);                             \
    P##c0 = ALD(ap_ + 32); P##c1 = ALD(ap_ + 33);                             \
    P##c2 = ALD(ap_ + 34); P##c3 = ALD(ap_ + 35);                             \
    P##d0 = ALD(ap_ + 48); P##d1 = ALD(ap_ + 49);                             \
    P##d2 = ALD(ap_ + 50); P##d3 = ALD(ap_ + 51);                             \
  }

#define HKC(E0, E1, E2, E3, KCG, ACC)                                         \
  {                                                                           \
    union { uint32_t u[4]; bf16x8 v; } fh_, fl_;                              \
    unpk2_(E0, fh_.u[0], fl_.u[0]);                                           \
    unpk2_(E1, fh_.u[1], fl_.u[1]);                                           \
    unpk2_(E2, fh_.u[2], fl_.u[2]);                                           \
    unpk2_(E3, fh_.u[3], fl_.u[3]);                                           \
    bf16x8 bh_ = WhH[((KCG) << 6) + lane];                                    \
    bf16x8 bl_ = WhL[((KCG) << 6) + lane];                                    \
    ACC = __builtin_amdgcn_mfma_f32_16x16x32_bf16(fh_.v, bh_, ACC, 0, 0, 0);  \
    ACC = __builtin_amdgcn_mfma_f32_16x16x32_bf16(fh_.v, bl_, ACC, 0, 0, 0);  \
    ACC = __builtin_amdgcn_mfma_f32_16x16x32_bf16(fl_.v, bh_, ACC, 0, 0, 0);  \
  }

#define HCOMP(P, CHk)                                                         \
  HKC(P##a0, P##a1, P##a2, P##a3, khb + (CHk) * 4 + 0, acc0)                  \
  HKC(P##b0, P##b1, P##b2, P##b3, khb + (CHk) * 4 + 1, acc1)                  \
  HKC(P##c0, P##c1, P##c2, P##c3, khb + (CHk) * 4 + 2, acc0)                  \
  HKC(P##d0, P##d1, P##d2, P##d3, khb + (CHk) * 4 + 3, acc1)

    HLD(p, 0)
    HLD(q, 1) HCOMP(p, 0)
    HLD(p, 2) HCOMP(q, 1)
    HLD(q, 3) HCOMP(p, 2)
    HCOMP(q, 3)
#undef HLD
#undef HKC
#undef HCOMP

    f32x4 accs = acc0 + acc1;
#pragma unroll
    for (int r = 0; r < 4; ++r)
      pre[((kh << 6) + (mt << 4) + dr + r) * 17 + dc] = accs[r];
    __syncthreads();

    if (tid < 256) {
      const uint4 xp = *reinterpret_cast<const uint4*>(
          xw_cur + (size_t)tl * 262144 + (size_t)bid * 1024 + en * 16 + ejj * 4);
      float a0 = pre[en * 17 + ejj] + pre[(64 + en) * 17 + ejj] +
                 bf2f_((ushort)(xp.x >> 16)) + bf2f_((ushort)(xp.x & 0xFFFF));
      float a1 = pre[en * 17 + 4 + ejj] + pre[(64 + en) * 17 + 4 + ejj] +
                 bf2f_((ushort)(xp.y >> 16)) + bf2f_((ushort)(xp.y & 0xFFFF));
      float a2 = pre[en * 17 + 8 + ejj] + pre[(64 + en) * 17 + 8 + ejj] +
                 bf2f_((ushort)(xp.z >> 16)) + bf2f_((ushort)(xp.z & 0xFFFF));
      float a3 = pre[en * 17 + 12 + ejj] + pre[(64 + en) * 17 + 12 + ejj] +
                 bf2f_((ushort)(xp.w >> 16)) + bf2f_((ushort)(xp.w & 0xFFFF));
      const int hx = en * H_ + (bid << 2) + ejj;
      float cp = (t == 0) ? 0.f : cbuf[hx];
      float iv = 1.f / (1.f + __expf(-a0));
      float fv = 1.f / (1.f + __expf(-a1));
      float ov = 1.f / (1.f + __expf(-a2));
      float gv = tanhf(a3);
      float cn = fmaf(fv, cp, iv * gv);
      cbuf[hx] = cn;
      float hn = ov * tanhf(cn);
      out[(size_t)en * ((size_t)T_ * H_) + (size_t)t * H_ + (bid << 2) + ejj] = hn;
      ushort hh = f2bf_(hn);
      uint32_t pk = ((uint32_t)hh << 16) | f2bf_(hn - bf2f_(hh));
      __hip_atomic_store(&hseq[(size_t)(t + 1) * 65536 + hx], pk,
                         __ATOMIC_RELAXED, __HIP_MEMORY_SCOPE_AGENT);
    }

    asm volatile("s_waitcnt vmcnt(0)" ::: "memory");
    __syncthreads();

    const unsigned tgt = (unsigned)(t + 1);
    if (tid == 0)
      __hip_atomic_store(&bar[bid], tgt, __ATOMIC_RELAXED,
                         __HIP_MEMORY_SCOPE_AGENT);
    if (bid == 0 && tid < 64) {
      const unsigned long long* fl = (const unsigned long long*)bar;
      for (;;) {
        unsigned long long v0 = __hip_atomic_load(fl + tid, __ATOMIC_RELAXED,
                                                  __HIP_MEMORY_SCOPE_AGENT);
        unsigned long long v1 = __hip_atomic_load(fl + 64 + tid, __ATOMIC_RELAXED,
                                                  __HIP_MEMORY_SCOPE_AGENT);
        bool ok = ((unsigned)v0 >= tgt) && ((unsigned)(v0 >> 32) >= tgt) &&
                  ((unsigned)v1 >= tgt) && ((unsigned)(v1 >> 32) >= tgt);
        if (__all((int)ok)) break;
      }
      if (tid < 8)
        __hip_atomic_store(bar + 384 + (tid << 5), tgt, __ATOMIC_RELAXED,
                           __HIP_MEMORY_SCOPE_AGENT);
    }
    if (tid == 0) {
      while (__hip_atomic_load(relmy, __ATOMIC_RELAXED,
                               __HIP_MEMORY_SCOPE_AGENT) < tgt)
        __builtin_amdgcn_s_sleep(1);
    }
    __syncthreads();
  }
}

// ---------------------------------------------------------------------------
// Fallback (tiny ws): fused per-step VALU kernel (round-1 proven). Slow.
// ---------------------------------------------------------------------------
__global__ __launch_bounds__(256) void lstm_step_fb(
    const float* __restrict__ xt, const float* __restrict__ Wx,
    const float* __restrict__ Wh, const float* __restrict__ bias,
    const float* __restrict__ h_prev, long long hstride,
    float* __restrict__ cbuf, float* __restrict__ h_out, int first) {
  __shared__ float hS[32][128];
  __shared__ float wT[32][132];
  __shared__ float pre[32][34];
  const int tid = threadIdx.x;
  const int colblk = blockIdx.x & 127;
  const int nh = blockIdx.x >> 7;
  const int j0 = colblk << 3;
  const int n0 = nh << 5;
  const int ng = tid >> 4, cg2 = tid & 15;
  const int na = ng << 1, ca = cg2 << 1;

  float acc[2][2] = {{0.f, 0.f}, {0.f, 0.f}};

#pragma unroll
  for (int pr = 0; pr < 2; ++pr) {
    const float* src = (pr == 0) ? h_prev : xt;
    long long sstr = (pr == 0) ? hstride : (long long)T_ * D_;
    const float* W = (pr == 0) ? Wh : Wx;
    for (int k0 = 0; k0 < 1024; k0 += 128) {
      __syncthreads();
#pragma unroll
      for (int p = 0; p < 4; ++p) {
        int idx = tid + (p << 8);
        int r = idx >> 5, c4 = (idx & 31) << 2;
        *reinterpret_cast<float4*>(&hS[r][c4]) =
            *reinterpret_cast<const float4*>(src + (size_t)(n0 + r) * sstr + k0 + c4);
      }
#pragma unroll
      for (int p = 0; p < 4; ++p) {
        int idx = tid + (p << 8);
        int k = idx >> 3, sub = idx & 7;
        int g = sub >> 1, hf = (sub & 1) << 2;
        float4 v = *reinterpret_cast<const float4*>(
            W + (size_t)(k0 + k) * FH + g * H_ + j0 + hf);
        int cb = (g << 3) + hf;
        wT[cb][k] = v.x; wT[cb + 1][k] = v.y; wT[cb + 2][k] = v.z; wT[cb + 3][k] = v.w;
      }
      __syncthreads();
#pragma unroll
      for (int kk = 0; kk < 128; kk += 4) {
        float4 h0v = *reinterpret_cast<const float4*>(&hS[na][kk]);
        float4 h1v = *reinterpret_cast<const float4*>(&hS[na + 1][kk]);
        float4 w0 = *reinterpret_cast<const float4*>(&wT[ca][kk]);
        float4 w1 = *reinterpret_cast<const float4*>(&wT[ca + 1][kk]);
        acc[0][0] = fmaf(h0v.x, w0.x, acc[0][0]); acc[0][0] = fmaf(h0v.y, w0.y, acc[0][0]);
        acc[0][0] = fmaf(h0v.z, w0.z, acc[0][0]); acc[0][0] = fmaf(h0v.w, w0.w, acc[0][0]);
        acc[0][1] = fmaf(h0v.x, w1.x, acc[0][1]); acc[0][1] = fmaf(h0v.y, w1.y, acc[0][1]);
        acc[0][1] = fmaf(h0v.z, w1.z, acc[0][1]); acc[0][1] = fmaf(h0v.w, w1.w, acc[0][1]);
        acc[1][0] = fmaf(h1v.x, w0.x, acc[1][0]); acc[1][0] = fmaf(h1v.y, w0.y, acc[1][0]);
        acc[1][0] = fmaf(h1v.z, w0.z, acc[1][0]); acc[1][0] = fmaf(h1v.w, w0.w, acc[1][0]);
        acc[1][1] = fmaf(h1v.x, w1.x, acc[1][1]); acc[1][1] = fmaf(h1v.y, w1.y, acc[1][1]);
        acc[1][1] = fmaf(h1v.z, w1.z, acc[1][1]); acc[1][1] = fmaf(h1v.w, w1.w, acc[1][1]);
      }
    }
  }

  pre[na][ca] = acc[0][0];
  pre[na][ca + 1] = acc[0][1];
  pre[na + 1][ca] = acc[1][0];
  pre[na + 1][ca + 1] = acc[1][1];
  __syncthreads();

  const int nl = tid >> 3, jl = tid & 7;
  const int n = n0 + nl;
  const int jg = j0 + jl;
  float ai = pre[nl][jl] + bias[jg];
  float af = pre[nl][8 + jl] + bias[H_ + jg];
  float ao = pre[nl][16 + jl] + bias[2 * H_ + jg];
  float ag = pre[nl][24 + jl] + bias[3 * H_ + jg];
  float cp = first ? 0.0f : cbuf[n * H_ + jg];
  float iv = 1.f / (1.f + __expf(-ai));
  float fv = 1.f / (1.f + __expf(-af));
  float ov = 1.f / (1.f + __expf(-ao));
  float gv = tanhf(ag);
  float cn = fmaf(fv, cp, iv * gv);
  cbuf[n * H_ + jg] = cn;
  h_out[(size_t)n * ((size_t)T_ * H_) + jg] = ov * tanhf(cn);
}

// ---------------------------------------------------------------------------
extern "C" void kernel_launch(void* const* d_in, const int* in_sizes, int n_in,
                              void* d_out, int out_size, void* d_ws, size_t ws_size,
                              hipStream_t stream) {
  (void)in_sizes; (void)n_in; (void)out_size;
  const float* x  = (const float*)d_in[0];
  const float* h0 = (const float*)d_in[1];
  const float* Wx = (const float*)d_in[2];
  const float* Wh = (const float*)d_in[3];
  const float* b  = (const float*)d_in[4];
  float* out = (float*)d_out;

  const size_t MB = 1u << 20;
  char* p = (char*)d_ws;

  if (ws_size >= 420 * MB) {
    unsigned* bar = (unsigned*)p;                // flags[256] + rel copies @+384
    ushort* Whh = (ushort*)(p + 1 * MB);
    ushort* Whl = (ushort*)(p + 9 * MB);
    ushort* Wxh = (ushort*)(p + 17 * MB);
    ushort* Wxl = (ushort*)(p + 25 * MB);
    uint32_t* hseq = (uint32_t*)(p + 33 * MB);   // 513 * 256 KB ≈ 128.25 MB
    float* cbuf = (float*)(p + 162 * MB);        // 256 KB
    ushort* xh = (ushort*)(p + 163 * MB);        // 64 MB
    ushort* xl = (ushort*)(p + 227 * MB);        // 64 MB
    uint32_t* xwp0 = (uint32_t*)(p + 291 * MB);  // 64 MB
    uint32_t* xwp1 = (uint32_t*)(p + 355 * MB);  // 64 MB (ends 419 MB)

    pack_w_k<<<dim3(2048), dim3(256), 0, stream>>>(Wh, Whh, Whl);
    pack_w_k<<<dim3(2048), dim3(256), 0, stream>>>(Wx, Wxh, Wxl);
    split_f32_k<<<dim3(32768), dim3(256), 0, stream>>>(x, xh, xl);
    conv_h0pk_k<<<dim3(64), dim3(256), 0, stream>>>(h0, hseq, bar);

    const unsigned SH = 2048 * 16 * 2 + 128 * 17 * 4;  // 74240 B
    hipFuncSetAttribute((const void*)lstm_fused_k,
                        hipFuncAttributeMaxDynamicSharedMemorySize, (int)SH);

    // chunk 0's xw via standalone GEMM, then 8 fused scan+next-gemm dispatches
    gemm_xw_mfma<<<dim3(16, 256), dim3(256), 0, stream>>>(Wxh, Wxl, xh, xl, b,
                                                          xwp0, 0);
    for (int c = 0; c < 8; ++c) {
      uint32_t* cur = (c & 1) ? xwp1 : xwp0;
      uint32_t* nxt = (c & 1) ? xwp0 : xwp1;
      lstm_fused_k<<<dim3(512), dim3(512), SH, stream>>>(
          Whh, Whl, Wxh, Wxl, xh, xl, b, cur, nxt, hseq, cbuf, out, bar,
          c * CH);
    }
  } else {
    float* cbuf = (float*)p;  // 256 KB
    for (int t = 0; t < T_; ++t) {
      const float* hp = (t == 0) ? h0 : out + (size_t)(t - 1) * H_;
      long long hstr = (t == 0) ? (long long)H_ : (long long)T_ * H_;
      lstm_step_fb<<<dim3(256), dim3(256), 0, stream>>>(
          x + (size_t)t * D_, Wx, Wh, b, hp, hstr, cbuf,
          out + (size_t)t * H_, t == 0);
    }
  }
}